// Round 3
// baseline (334.962 us; speedup 1.0000x reference)
//
#include <hip/hip_runtime.h>
#include <hip/hip_bf16.h>

typedef __attribute__((ext_vector_type(8))) short short8;
typedef __attribute__((ext_vector_type(4))) short short4v;
typedef __attribute__((ext_vector_type(4))) float f32x4;
typedef __hip_bfloat16 bf16;

#define SEQ 2048
#define DIM 2048
#define NH 32
#define NKV 8
#define HD 64
#define QKVD 3072
#define KVD 512
#define SMSCALE 0.18033688011112042f  /* 0.125 * log2(e), folded into Q at rope time */

__device__ inline void gld_lds16(const bf16* g, bf16* l) {
    __builtin_amdgcn_global_load_lds((const __attribute__((address_space(1))) void*)g,
                                     (__attribute__((address_space(3))) void*)l, 16, 0, 0);
}

__device__ inline void store_val(float* p, float v) { *p = v; }
__device__ inline void store_val(bf16* p, float v) { *p = __float2bfloat16(v); }

__device__ inline unsigned pkbf16(float a, float b) {
    __hip_bfloat162 h = __float22bfloat162_rn(make_float2(a, b));
    return *(unsigned*)&h;
}

__device__ inline float b2f(short x) {
    unsigned u = (unsigned)(unsigned short)x << 16;
    union { unsigned u; float f; } c; c.u = u; return c.f;
}

// ---------------- fused fp32 -> bf16 convert for x | wqkv | wo ----------------
__global__ void cvt3_kernel(const float* __restrict__ x, const float* __restrict__ wqkv,
                            const float* __restrict__ wo, bf16* __restrict__ out) {
    int i = blockIdx.x * blockDim.x + threadIdx.x;
    const float* src; int off;
    if (i < 2097152) { src = x; off = i; }
    else if (i < 3670016) { src = wqkv; off = i - 2097152; }
    else { src = wo; off = i - 3670016; }
    float4 v = ((const float4*)src)[off];
    uint2 u;
    u.x = pkbf16(v.x, v.y);
    u.y = pkbf16(v.z, v.w);
    ((uint2*)out)[i] = u;
}

// ---------------- 8-phase 256x256 NT GEMM (T1-free, T2+T3+T4+T5) ----------------
// C[M,N] = A[M,K]*Bt[N,K]^T. BM=BN=256, BK=64, 512 threads = 8 waves (2M x 4N),
// per-wave 128x64 output as 4 scattered quadrants. LDS 128KB (2 dbuf x (A 32K + B 32K)).
// Per K-tile: 4 phases {ds_read subtile | stage 1 half-tile (2 gld_lds) | vmcnt(4) |
// barrier | lgkm0 | setprio1 | 16 MFMA | setprio0 | barrier}.
// Compute order Q00,Q10,Q11,Q01 + stage order A0,B0,A1,B1 gives every staged half a
// 3-4 phase stage->read gap, so uniform vmcnt(4) never waits on a fresh load (T4:
// counted, never 0 in main loop; one vmcnt(0) in prologue only).
// T2 swizzle: LDS[row][col ^ (row&7)*8]; staged via inverse-swizzled GLOBAL source
// (rule #21: global_load_lds dest must stay linear), read with same XOR -> b128
// reads hit 8 distinct 16B slots per 16 lanes = conflict-free.
template <typename CT>
__global__ __launch_bounds__(512, 2) void gemm8p(const bf16* __restrict__ A,
                                                 const bf16* __restrict__ Bt,
                                                 CT* __restrict__ C,
                                                 int N, int K) {
    __shared__ bf16 Abuf[2][16384];
    __shared__ bf16 Bbuf[2][16384];
    const int tid = threadIdx.x;
    const int lane = tid & 63;
    const int quad = lane >> 4;
    const int r16 = lane & 15;
    const int wv = tid >> 6;
    const int wm = wv >> 2;        // 0..1
    const int wn = wv & 3;         // 0..3
    const int bm = blockIdx.y * 256;
    const int bn = blockIdx.x * 256;
    const int swz = (lane & 7) * 8;   // read-side XOR: (R&7)*8 with R = base16*k + r16

    // staging: thread t covers (row = t>>3 [+64c], global col = ((t&7) ^ ((t>>3)&7))*8)
    const int sc = (((tid & 7) ^ ((tid >> 3) & 7)) * 8);
    const bf16* Ap = A + (size_t)(bm + (tid >> 3)) * K + sc;
    const bf16* Bp = Bt + (size_t)(bn + (tid >> 3)) * K + sc;

    f32x4 acc[8][4] = {};
    const int NT = K >> 6;

    // prologue: stage tile 0 fully (A0,B0,A1,B1), single drain
    {
        bf16* Ad = &Abuf[0][0] + tid * 8;
        bf16* Bd = &Bbuf[0][0] + tid * 8;
        gld_lds16(Ap, Ad);                          gld_lds16(Ap + (size_t)64 * K, Ad + 4096);
        gld_lds16(Bp, Bd);                          gld_lds16(Bp + (size_t)64 * K, Bd + 4096);
        gld_lds16(Ap + (size_t)128 * K, Ad + 8192); gld_lds16(Ap + (size_t)192 * K, Ad + 12288);
        gld_lds16(Bp + (size_t)128 * K, Bd + 8192); gld_lds16(Bp + (size_t)192 * K, Bd + 12288);
    }
    asm volatile("s_waitcnt vmcnt(0)" ::: "memory");
    __builtin_amdgcn_s_barrier();

    short8 af[4][2], af2[4][2], bf0[2][2], bf1[2][2];

#define GPH_MID \
    asm volatile("s_waitcnt vmcnt(4)" ::: "memory"); \
    __builtin_amdgcn_s_barrier(); \
    asm volatile("s_waitcnt lgkmcnt(0)" ::: "memory"); \
    __builtin_amdgcn_s_setprio(1)
#define GPH_END \
    __builtin_amdgcn_s_setprio(0); \
    __builtin_amdgcn_s_barrier()
#define MFMA_BF16(a, b, c) __builtin_amdgcn_mfma_f32_16x16x32_bf16(a, b, c, 0, 0, 0)

#pragma unroll 1
    for (int t = 0; t < NT; t++) {
        const bf16* Ac = &Abuf[t & 1][0];
        const bf16* Bc = &Bbuf[t & 1][0];
        bf16* Ad = &Abuf[(t & 1) ^ 1][0] + tid * 8;
        bf16* Bd = &Bbuf[(t & 1) ^ 1][0] + tid * 8;
        const bf16* Apn = Ap + (size_t)(t + 1) * 64;
        const bf16* Bpn = Bp + (size_t)(t + 1) * 64;
        const bool stg = (t + 1 < NT);

        // ---- Phase 1: read af (A-h0) + bf0 (B-h0); stage A-h0(next); MFMA Q00 ----
#pragma unroll
        for (int i = 0; i < 4; i++) {
            const bf16* p = Ac + (wm * 64 + i * 16 + r16) * 64;
            af[i][0] = *(const short8*)(p + ((quad * 8) ^ swz));
            af[i][1] = *(const short8*)(p + ((32 + quad * 8) ^ swz));
        }
#pragma unroll
        for (int j = 0; j < 2; j++) {
            const bf16* p = Bc + (wn * 32 + j * 16 + r16) * 64;
            bf0[j][0] = *(const short8*)(p + ((quad * 8) ^ swz));
            bf0[j][1] = *(const short8*)(p + ((32 + quad * 8) ^ swz));
        }
        if (stg) { gld_lds16(Apn, Ad); gld_lds16(Apn + (size_t)64 * K, Ad + 4096); }
        GPH_MID;
#pragma unroll
        for (int i = 0; i < 4; i++)
#pragma unroll
            for (int j = 0; j < 2; j++) {
                acc[i][j] = MFMA_BF16(af[i][0], bf0[j][0], acc[i][j]);
                acc[i][j] = MFMA_BF16(af[i][1], bf0[j][1], acc[i][j]);
            }
        GPH_END;

        // ---- Phase 2: read af2 (A-h1); stage B-h0(next); MFMA Q10 ----
#pragma unroll
        for (int i = 0; i < 4; i++) {
            const bf16* p = Ac + (128 + wm * 64 + i * 16 + r16) * 64;
            af2[i][0] = *(const short8*)(p + ((quad * 8) ^ swz));
            af2[i][1] = *(const short8*)(p + ((32 + quad * 8) ^ swz));
        }
        if (stg) { gld_lds16(Bpn, Bd); gld_lds16(Bpn + (size_t)64 * K, Bd + 4096); }
        GPH_MID;
#pragma unroll
        for (int i = 0; i < 4; i++)
#pragma unroll
            for (int j = 0; j < 2; j++) {
                acc[4 + i][j] = MFMA_BF16(af2[i][0], bf0[j][0], acc[4 + i][j]);
                acc[4 + i][j] = MFMA_BF16(af2[i][1], bf0[j][1], acc[4 + i][j]);
            }
        GPH_END;

        // ---- Phase 3: read bf1 (B-h1); stage A-h1(next); MFMA Q11 ----
#pragma unroll
        for (int j = 0; j < 2; j++) {
            const bf16* p = Bc + (128 + wn * 32 + j * 16 + r16) * 64;
            bf1[j][0] = *(const short8*)(p + ((quad * 8) ^ swz));
            bf1[j][1] = *(const short8*)(p + ((32 + quad * 8) ^ swz));
        }
        if (stg) { gld_lds16(Apn + (size_t)128 * K, Ad + 8192); gld_lds16(Apn + (size_t)192 * K, Ad + 12288); }
        GPH_MID;
#pragma unroll
        for (int i = 0; i < 4; i++)
#pragma unroll
            for (int j = 0; j < 2; j++) {
                acc[4 + i][2 + j] = MFMA_BF16(af2[i][0], bf1[j][0], acc[4 + i][2 + j]);
                acc[4 + i][2 + j] = MFMA_BF16(af2[i][1], bf1[j][1], acc[4 + i][2 + j]);
            }
        GPH_END;

        // ---- Phase 4: no reads; stage B-h1(next); MFMA Q01 ----
        if (stg) { gld_lds16(Bpn + (size_t)128 * K, Bd + 8192); gld_lds16(Bpn + (size_t)192 * K, Bd + 12288); }
        GPH_MID;
#pragma unroll
        for (int i = 0; i < 4; i++)
#pragma unroll
            for (int j = 0; j < 2; j++) {
                acc[i][2 + j] = MFMA_BF16(af[i][0], bf1[j][0], acc[i][2 + j]);
                acc[i][2 + j] = MFMA_BF16(af[i][1], bf1[j][1], acc[i][2 + j]);
            }
        GPH_END;
    }

    // epilogue: C-write (layout verified: row += quad*4 + r, col += r16)
#pragma unroll
    for (int i = 0; i < 8; i++) {
        int row = bm + (i < 4 ? wm * 64 + i * 16 : 128 + wm * 64 + (i - 4) * 16) + quad * 4;
#pragma unroll
        for (int j = 0; j < 4; j++) {
            int col = bn + wn * 32 + (j < 2 ? j * 16 : 128 + (j - 2) * 16) + r16;
#pragma unroll
            for (int r = 0; r < 4; r++)
                store_val(C + (size_t)(row + r) * N + col, acc[i][j][r]);
        }
    }
#undef GPH_MID
#undef GPH_END
#undef MFMA_BF16
}

// ---------------- RoPE on Q,K, vectorized x8 (Q pre-scaled by SMSCALE) ----------------
__global__ void rope_qk_kernel(const bf16* __restrict__ qkv, const float* __restrict__ fc,
                               bf16* __restrict__ qr, bf16* __restrict__ kr) {
    const int row = blockIdx.y;
    const int s = row & (SEQ - 1);
    const int col = (blockIdx.x * 64 + threadIdx.x) * 8;  // 0..2552, step 8
    const bf16* src = qkv + (size_t)row * QKVD + col;
    short8 v = *(const short8*)src;
    const int j0 = (col & 63) >> 1;
    const float4* fcp = (const float4*)(fc + ((size_t)s * 32 + j0) * 2);
    float4 f01 = fcp[0];
    float4 f23 = fcp[1];

    bf16* dst;
    float sc;
    if (col < DIM) { dst = qr + (size_t)row * DIM + col; sc = SMSCALE; }
    else           { dst = kr + (size_t)row * KVD + (col - DIM); sc = 1.0f; }

    float x0 = b2f(v[0]), x1 = b2f(v[1]), x2 = b2f(v[2]), x3 = b2f(v[3]);
    float x4 = b2f(v[4]), x5 = b2f(v[5]), x6 = b2f(v[6]), x7 = b2f(v[7]);
    float c0 = f01.x * sc, s0 = f01.y * sc, c1 = f01.z * sc, s1 = f01.w * sc;
    float c2 = f23.x * sc, s2 = f23.y * sc, c3 = f23.z * sc, s3 = f23.w * sc;

    uint4 o;
    o.x = pkbf16(x0 * c0 - x1 * s0, x1 * c0 + x0 * s0);
    o.y = pkbf16(x2 * c1 - x3 * s1, x3 * c1 + x2 * s1);
    o.z = pkbf16(x4 * c2 - x5 * s2, x5 * c2 + x4 * s2);
    o.w = pkbf16(x6 * c3 - x7 * s3, x7 * c3 + x6 * s3);
    *(uint4*)dst = o;
}

// ---------------- V transpose: qkv[s][2560+kvh*64+d] -> vt[(b,kvh,d)][s] ----------------
__global__ void rope_v_kernel(const bf16* __restrict__ qkv, bf16* __restrict__ vt) {
    const int t = threadIdx.x;
    const int so = t & 63;
    const int dq = t >> 6;
    const int bk = blockIdx.y;
    const int s = blockIdx.x * 64 + so;
    const int b = bk >> 3;
    const bf16* src = qkv + ((size_t)b * SEQ + s) * QKVD + DIM + KVD + (bk & 7) * HD + dq * 16;
    short8 v0 = *(const short8*)src;
    short8 v1 = *(const short8*)(src + 8);
    short* dst = (short*)(vt + ((size_t)bk * HD + dq * 16) * SEQ + s);
#pragma unroll
    for (int j = 0; j < 8; j++) dst[(size_t)j * SEQ] = v0[j];
#pragma unroll
    for (int j = 0; j < 8; j++) dst[(size_t)(8 + j) * SEQ] = v1[j];
}

// ---------------- Flash attention (unchanged from round 2: 93.9 us verified) ----------------
__global__ __launch_bounds__(256, 4) void attn_kernel(const bf16* __restrict__ qr,
                                                      const bf16* __restrict__ kr,
                                                      const bf16* __restrict__ vt,
                                                      bf16* __restrict__ out) {
    __shared__ bf16 Ks[8192];
    __shared__ bf16 Vs[8192];
    const int t = threadIdx.x;
    const int lane = t & 63;
    const int wv = t >> 6;
    const int quad = lane >> 4;
    const int r16 = lane & 15;

    const int wg = blockIdx.x;
    const int xcd = wg & 7;
    const int kk = wg >> 3;
    const int bk = xcd * 2 + (kk & 1);
    const int qt = 127 - (kk >> 1);
    const int b = bk >> 3;
    const int kvh = bk & 7;
    const int h = kvh * 4 + wv;
    const int q0 = qt * 16;
    const int nkb = (qt >> 2) + 1;

    const bf16* Kg = kr + ((size_t)b * SEQ + lane) * KVD + kvh * HD + wv * 8;
    const bf16* Vg = vt + ((size_t)(b * NKV + kvh) * HD + lane) * SEQ + wv * 8;

    const char* kl = (const char*)Ks + quad * 1024 + r16 * 16;
    const char* vl = (const char*)Vs + (quad >> 1) * 1024 + r16 * 16 + (quad & 1) * 8;

    union PB { short4v s; unsigned u[2]; };

    const short one_bf16 = (short)0x3F80;
    const short4v ones = {one_bf16, one_bf16, one_bf16, one_bf16};

    const bf16* Qp = qr + ((size_t)b * SEQ + q0 + r16) * DIM + h * HD + quad * 8;
    short8 qa0 = *(const short8*)(Qp);
    short8 qa1 = *(const short8*)(Qp + 32);

    f32x4 o[4] = {};
    f32x4 o_l = {};

    {
        bf16* Ksd = Ks + t * 8;
        bf16* Vsd = Vs + t * 8;
        gld_lds16(Kg, Ksd);      gld_lds16(Kg + 32, Ksd + 2048);
        gld_lds16(Vg, Vsd);      gld_lds16(Vg + 32, Vsd + 2048);
    }

    for (int kb = 0; kb < nkb; kb++) {
        __syncthreads();
        const int buf = kb & 1;
        if (kb + 1 < nkb) {
            const bf16* Kgn = Kg + (size_t)(kb + 1) * 64 * KVD;
            const bf16* Vgn = Vg + (kb + 1) * 64;
            bf16* Ksd = Ks + (buf ^ 1) * 4096 + t * 8;
            bf16* Vsd = Vs + (buf ^ 1) * 4096 + t * 8;
            gld_lds16(Kgn, Ksd);      gld_lds16(Kgn + 32, Ksd + 2048);
            gld_lds16(Vgn, Vsd);      gld_lds16(Vgn + 32, Vsd + 2048);
        }
        const char* klb = kl + buf * 8192;
        const char* vlb = vl + buf * 8192;

        const f32x4 z = {0.f, 0.f, 0.f, 0.f};
        f32x4 st[4];
        __builtin_amdgcn_s_setprio(1);
#pragma unroll
        for (int n = 0; n < 4; n++) {
            short8 kf0 = *(const short8*)(klb + n * 256);
            short8 kf1 = *(const short8*)(klb + 4096 + n * 256);
            st[n] = __builtin_amdgcn_mfma_f32_16x16x32_bf16(kf0, qa0, z, 0, 0, 0);
            st[n] = __builtin_amdgcn_mfma_f32_16x16x32_bf16(kf1, qa1, st[n], 0, 0, 0);
        }
        __builtin_amdgcn_s_setprio(0);

        short4v vf[4][4];
#pragma unroll
        for (int dt = 0; dt < 4; dt++)
#pragma unroll
            for (int n = 0; n < 4; n++)
                vf[dt][n] = *(const short4v*)(vlb + n * 2048 + dt * 256);
        __builtin_amdgcn_sched_barrier(0);

        if (kb == nkb - 1) {
            const int kbase = kb * 64;
#pragma unroll
            for (int n = 0; n < 4; n++)
#pragma unroll
                for (int r = 0; r < 4; r++) {
                    int key = kbase + n * 16 + quad * 4 + r;
                    if (key > q0 + r16) st[n][r] = -__builtin_inff();
                }
        }

        PB pbs[4];
#pragma unroll
        for (int n = 0; n < 4; n++) {
            float p0 = exp2f(st[n][0]);
            float p1 = exp2f(st[n][1]);
            float p2 = exp2f(st[n][2]);
            float p3 = exp2f(st[n][3]);
            pbs[n].u[0] = pkbf16(p0, p1);
            pbs[n].u[1] = pkbf16(p2, p3);
        }

        __builtin_amdgcn_s_setprio(1);
#pragma unroll
        for (int dt = 0; dt < 4; dt++)
#pragma unroll
            for (int n = 0; n < 4; n++)
                o[dt] = __builtin_amdgcn_mfma_f32_16x16x16bf16_1k(vf[dt][n], pbs[n].s, o[dt], 0, 0, 0);
#pragma unroll
        for (int n = 0; n < 4; n++)
            o_l = __builtin_amdgcn_mfma_f32_16x16x16bf16_1k(ones, pbs[n].s, o_l, 0, 0, 0);
        __builtin_amdgcn_s_setprio(0);
    }

    float inv_l = 1.f / o_l[0];
    bf16* Op = out + ((size_t)b * SEQ + q0 + r16) * DIM + h * HD + quad * 4;
#pragma unroll
    for (int dt = 0; dt < 4; dt++) {
        PB pk;
        pk.u[0] = pkbf16(o[dt][0] * inv_l, o[dt][1] * inv_l);
        pk.u[1] = pkbf16(o[dt][2] * inv_l, o[dt][3] * inv_l);
        *(short4v*)(Op + dt * 16) = pk.s;
    }
}

extern "C" void kernel_launch(void* const* d_in, const int* in_sizes, int n_in,
                              void* d_out, int out_size, void* d_ws, size_t ws_size,
                              hipStream_t stream) {
    (void)in_sizes; (void)n_in; (void)out_size; (void)ws_size;
    const float* x    = (const float*)d_in[0];
    const float* fc   = (const float*)d_in[1];
    const float* wqkv = (const float*)d_in[3];
    const float* wo   = (const float*)d_in[4];
    float* out = (float*)d_out;

    char* w = (char*)d_ws;
    bf16* xb    = (bf16*)(w);
    bf16* wqkvb = (bf16*)(w + 16777216);
    bf16* wob   = (bf16*)(w + 29360128);
    bf16* qkvb  = (bf16*)(w + 37748736);
    bf16* kr    = (bf16*)(w + 62914560);
    bf16* vt    = (bf16*)(w + 67108864);
    bf16* qr = xb;
    bf16* attnb = qkvb;

    cvt3_kernel<<<18432, 256, 0, stream>>>(x, wqkv, wo, xb);
    gemm8p<bf16><<<dim3(12, 16), 512, 0, stream>>>(xb, wqkvb, qkvb, QKVD, DIM);
    rope_qk_kernel<<<dim3(5, 4096), 64, 0, stream>>>(qkvb, fc, qr, kr);
    rope_v_kernel<<<dim3(32, 16), 256, 0, stream>>>(qkvb, vt);
    attn_kernel<<<dim3(2048), 256, 0, stream>>>(qr, kr, vt, attnb);
    gemm8p<float><<<dim3(8, 16), 512, 0, stream>>>(attnb, wob, out, DIM, DIM);
}

// Round 4
// 324.371 us; speedup vs baseline: 1.0327x; 1.0327x over previous
//
#include <hip/hip_runtime.h>
#include <hip/hip_bf16.h>

typedef __attribute__((ext_vector_type(8))) short short8;
typedef __attribute__((ext_vector_type(4))) short short4v;
typedef __attribute__((ext_vector_type(4))) float f32x4;
typedef __hip_bfloat16 bf16;

#define SEQ 2048
#define DIM 2048
#define NH 32
#define NKV 8
#define HD 64
#define QKVD 3072
#define KVD 512
#define SMSCALE 0.18033688011112042f  /* 0.125 * log2(e), folded into Q at rope time */

__device__ inline void gld_lds16(const bf16* g, bf16* l) {
    __builtin_amdgcn_global_load_lds((const __attribute__((address_space(1))) void*)g,
                                     (__attribute__((address_space(3))) void*)l, 16, 0, 0);
}

__device__ inline void store_val(float* p, float v) { *p = v; }
__device__ inline void store_val(bf16* p, float v) { *p = __float2bfloat16(v); }

__device__ inline unsigned pkbf16(float a, float b) {
    __hip_bfloat162 h = __float22bfloat162_rn(make_float2(a, b));
    return *(unsigned*)&h;
}

__device__ inline float b2f(short x) {
    unsigned u = (unsigned)(unsigned short)x << 16;
    union { unsigned u; float f; } c; c.u = u; return c.f;
}

// ---------------- fused fp32 -> bf16 convert for x | wqkv | wo ----------------
__global__ void cvt3_kernel(const float* __restrict__ x, const float* __restrict__ wqkv,
                            const float* __restrict__ wo, bf16* __restrict__ out) {
    int i = blockIdx.x * blockDim.x + threadIdx.x;
    const float* src; int off;
    if (i < 2097152) { src = x; off = i; }
    else if (i < 3670016) { src = wqkv; off = i - 2097152; }
    else { src = wo; off = i - 3670016; }
    float4 v = ((const float4*)src)[off];
    uint2 u;
    u.x = pkbf16(v.x, v.y);
    u.y = pkbf16(v.z, v.w);
    ((uint2*)out)[i] = u;
}

// ---------------- NT GEMM: C[M,N] = A[M,K] * Bt[N,K]^T  (m97 structure) ----------------
// Used for wo (M=4096,N=2048): grid 16x32 = 512 blocks = 2/CU, 100% chip fill.
template <typename CT>
__global__ __launch_bounds__(256, 3) void gemm_nt(const bf16* __restrict__ A,
                                                  const bf16* __restrict__ Bt,
                                                  CT* __restrict__ C,
                                                  int M, int N, int K) {
    __shared__ bf16 As[128 * 32];
    __shared__ bf16 Bs[128 * 32];
    const int tid = threadIdx.x;
    const int lane = tid & 63;
    const int quad = lane >> 4;
    const int r16 = lane & 15;
    const int wave = tid >> 6;
    const int bm = blockIdx.y * 128;
    const int bn = blockIdx.x * 128;
    const int wm = (wave >> 1) * 64;
    const int wn = (wave & 1) * 64;

    f32x4 acc[4][4] = {};

    const int arow = tid >> 2;
    const int kch = (tid & 3) * 8;
    const bf16* Ap = A + (size_t)(bm + arow) * K + kch;
    const bf16* Bp = Bt + (size_t)(bn + arow) * K + kch;
    bf16* Asd = As + tid * 8;
    bf16* Bsd = Bs + tid * 8;
    const int kq = quad * 8;

    for (int k0 = 0; k0 < K; k0 += 32) {
        __syncthreads();
        gld_lds16(Ap, Asd);
        gld_lds16(Ap + (size_t)64 * K, Asd + 64 * 32);
        gld_lds16(Bp, Bsd);
        gld_lds16(Bp + (size_t)64 * K, Bsd + 64 * 32);
        Ap += 32; Bp += 32;
        __syncthreads();
        short8 af[4], bfr[4];
#pragma unroll
        for (int i = 0; i < 4; i++)
            af[i] = *(const short8*)(As + (wm + i * 16 + r16) * 32 + kq);
#pragma unroll
        for (int j = 0; j < 4; j++)
            bfr[j] = *(const short8*)(Bs + (wn + j * 16 + r16) * 32 + kq);
#pragma unroll
        for (int i = 0; i < 4; i++)
#pragma unroll
            for (int j = 0; j < 4; j++)
                acc[i][j] = __builtin_amdgcn_mfma_f32_16x16x32_bf16(af[i], bfr[j], acc[i][j], 0, 0, 0);
    }
#pragma unroll
    for (int i = 0; i < 4; i++)
#pragma unroll
        for (int j = 0; j < 4; j++) {
            int row = bm + wm + i * 16 + quad * 4;
            int col = bn + wn + j * 16 + r16;
#pragma unroll
            for (int r = 0; r < 4; r++)
                store_val(C + (size_t)(row + r) * N + col, acc[i][j][r]);
        }
}

// ---------------- 8-phase 256x256 NT GEMM (T2+T3+T4+T5) -- BYTE-IDENTICAL to round 3 ----------------
// Used for qkv only this round (A/B attribution vs gemm_nt).
template <typename CT>
__global__ __launch_bounds__(512, 2) void gemm8p(const bf16* __restrict__ A,
                                                 const bf16* __restrict__ Bt,
                                                 CT* __restrict__ C,
                                                 int N, int K) {
    __shared__ bf16 Abuf[2][16384];
    __shared__ bf16 Bbuf[2][16384];
    const int tid = threadIdx.x;
    const int lane = tid & 63;
    const int quad = lane >> 4;
    const int r16 = lane & 15;
    const int wv = tid >> 6;
    const int wm = wv >> 2;        // 0..1
    const int wn = wv & 3;         // 0..3
    const int bm = blockIdx.y * 256;
    const int bn = blockIdx.x * 256;
    const int swz = (lane & 7) * 8;

    const int sc = (((tid & 7) ^ ((tid >> 3) & 7)) * 8);
    const bf16* Ap = A + (size_t)(bm + (tid >> 3)) * K + sc;
    const bf16* Bp = Bt + (size_t)(bn + (tid >> 3)) * K + sc;

    f32x4 acc[8][4] = {};
    const int NT = K >> 6;

    {
        bf16* Ad = &Abuf[0][0] + tid * 8;
        bf16* Bd = &Bbuf[0][0] + tid * 8;
        gld_lds16(Ap, Ad);                          gld_lds16(Ap + (size_t)64 * K, Ad + 4096);
        gld_lds16(Bp, Bd);                          gld_lds16(Bp + (size_t)64 * K, Bd + 4096);
        gld_lds16(Ap + (size_t)128 * K, Ad + 8192); gld_lds16(Ap + (size_t)192 * K, Ad + 12288);
        gld_lds16(Bp + (size_t)128 * K, Bd + 8192); gld_lds16(Bp + (size_t)192 * K, Bd + 12288);
    }
    asm volatile("s_waitcnt vmcnt(0)" ::: "memory");
    __builtin_amdgcn_s_barrier();

    short8 af[4][2], af2[4][2], bf0[2][2], bf1[2][2];

#define GPH_MID \
    asm volatile("s_waitcnt vmcnt(4)" ::: "memory"); \
    __builtin_amdgcn_s_barrier(); \
    asm volatile("s_waitcnt lgkmcnt(0)" ::: "memory"); \
    __builtin_amdgcn_s_setprio(1)
#define GPH_END \
    __builtin_amdgcn_s_setprio(0); \
    __builtin_amdgcn_s_barrier()
#define MFMA_BF16(a, b, c) __builtin_amdgcn_mfma_f32_16x16x32_bf16(a, b, c, 0, 0, 0)

#pragma unroll 1
    for (int t = 0; t < NT; t++) {
        const bf16* Ac = &Abuf[t & 1][0];
        const bf16* Bc = &Bbuf[t & 1][0];
        bf16* Ad = &Abuf[(t & 1) ^ 1][0] + tid * 8;
        bf16* Bd = &Bbuf[(t & 1) ^ 1][0] + tid * 8;
        const bf16* Apn = Ap + (size_t)(t + 1) * 64;
        const bf16* Bpn = Bp + (size_t)(t + 1) * 64;
        const bool stg = (t + 1 < NT);

#pragma unroll
        for (int i = 0; i < 4; i++) {
            const bf16* p = Ac + (wm * 64 + i * 16 + r16) * 64;
            af[i][0] = *(const short8*)(p + ((quad * 8) ^ swz));
            af[i][1] = *(const short8*)(p + ((32 + quad * 8) ^ swz));
        }
#pragma unroll
        for (int j = 0; j < 2; j++) {
            const bf16* p = Bc + (wn * 32 + j * 16 + r16) * 64;
            bf0[j][0] = *(const short8*)(p + ((quad * 8) ^ swz));
            bf0[j][1] = *(const short8*)(p + ((32 + quad * 8) ^ swz));
        }
        if (stg) { gld_lds16(Apn, Ad); gld_lds16(Apn + (size_t)64 * K, Ad + 4096); }
        GPH_MID;
#pragma unroll
        for (int i = 0; i < 4; i++)
#pragma unroll
            for (int j = 0; j < 2; j++) {
                acc[i][j] = MFMA_BF16(af[i][0], bf0[j][0], acc[i][j]);
                acc[i][j] = MFMA_BF16(af[i][1], bf0[j][1], acc[i][j]);
            }
        GPH_END;

#pragma unroll
        for (int i = 0; i < 4; i++) {
            const bf16* p = Ac + (128 + wm * 64 + i * 16 + r16) * 64;
            af2[i][0] = *(const short8*)(p + ((quad * 8) ^ swz));
            af2[i][1] = *(const short8*)(p + ((32 + quad * 8) ^ swz));
        }
        if (stg) { gld_lds16(Bpn, Bd); gld_lds16(Bpn + (size_t)64 * K, Bd + 4096); }
        GPH_MID;
#pragma unroll
        for (int i = 0; i < 4; i++)
#pragma unroll
            for (int j = 0; j < 2; j++) {
                acc[4 + i][j] = MFMA_BF16(af2[i][0], bf0[j][0], acc[4 + i][j]);
                acc[4 + i][j] = MFMA_BF16(af2[i][1], bf0[j][1], acc[4 + i][j]);
            }
        GPH_END;

#pragma unroll
        for (int j = 0; j < 2; j++) {
            const bf16* p = Bc + (128 + wn * 32 + j * 16 + r16) * 64;
            bf1[j][0] = *(const short8*)(p + ((quad * 8) ^ swz));
            bf1[j][1] = *(const short8*)(p + ((32 + quad * 8) ^ swz));
        }
        if (stg) { gld_lds16(Apn + (size_t)128 * K, Ad + 8192); gld_lds16(Apn + (size_t)192 * K, Ad + 12288); }
        GPH_MID;
#pragma unroll
        for (int i = 0; i < 4; i++)
#pragma unroll
            for (int j = 0; j < 2; j++) {
                acc[4 + i][2 + j] = MFMA_BF16(af2[i][0], bf1[j][0], acc[4 + i][2 + j]);
                acc[4 + i][2 + j] = MFMA_BF16(af2[i][1], bf1[j][1], acc[4 + i][2 + j]);
            }
        GPH_END;

        if (stg) { gld_lds16(Bpn + (size_t)128 * K, Bd + 8192); gld_lds16(Bpn + (size_t)192 * K, Bd + 12288); }
        GPH_MID;
#pragma unroll
        for (int i = 0; i < 4; i++)
#pragma unroll
            for (int j = 0; j < 2; j++) {
                acc[i][2 + j] = MFMA_BF16(af[i][0], bf1[j][0], acc[i][2 + j]);
                acc[i][2 + j] = MFMA_BF16(af[i][1], bf1[j][1], acc[i][2 + j]);
            }
        GPH_END;
    }

#pragma unroll
    for (int i = 0; i < 8; i++) {
        int row = bm + (i < 4 ? wm * 64 + i * 16 : 128 + wm * 64 + (i - 4) * 16) + quad * 4;
#pragma unroll
        for (int j = 0; j < 4; j++) {
            int col = bn + wn * 32 + (j < 2 ? j * 16 : 128 + (j - 2) * 16) + r16;
#pragma unroll
            for (int r = 0; r < 4; r++)
                store_val(C + (size_t)(row + r) * N + col, acc[i][j][r]);
        }
    }
#undef GPH_MID
#undef GPH_END
#undef MFMA_BF16
}

// ---------------- RoPE on Q,K, vectorized x8 (Q pre-scaled by SMSCALE) ----------------
__global__ void rope_qk_kernel(const bf16* __restrict__ qkv, const float* __restrict__ fc,
                               bf16* __restrict__ qr, bf16* __restrict__ kr) {
    const int row = blockIdx.y;
    const int s = row & (SEQ - 1);
    const int col = (blockIdx.x * 64 + threadIdx.x) * 8;  // 0..2552, step 8
    const bf16* src = qkv + (size_t)row * QKVD + col;
    short8 v = *(const short8*)src;
    const int j0 = (col & 63) >> 1;
    const float4* fcp = (const float4*)(fc + ((size_t)s * 32 + j0) * 2);
    float4 f01 = fcp[0];
    float4 f23 = fcp[1];

    bf16* dst;
    float sc;
    if (col < DIM) { dst = qr + (size_t)row * DIM + col; sc = SMSCALE; }
    else           { dst = kr + (size_t)row * KVD + (col - DIM); sc = 1.0f; }

    float x0 = b2f(v[0]), x1 = b2f(v[1]), x2 = b2f(v[2]), x3 = b2f(v[3]);
    float x4 = b2f(v[4]), x5 = b2f(v[5]), x6 = b2f(v[6]), x7 = b2f(v[7]);
    float c0 = f01.x * sc, s0 = f01.y * sc, c1 = f01.z * sc, s1 = f01.w * sc;
    float c2 = f23.x * sc, s2 = f23.y * sc, c3 = f23.z * sc, s3 = f23.w * sc;

    uint4 o;
    o.x = pkbf16(x0 * c0 - x1 * s0, x1 * c0 + x0 * s0);
    o.y = pkbf16(x2 * c1 - x3 * s1, x3 * c1 + x2 * s1);
    o.z = pkbf16(x4 * c2 - x5 * s2, x5 * c2 + x4 * s2);
    o.w = pkbf16(x6 * c3 - x7 * s3, x7 * c3 + x6 * s3);
    *(uint4*)dst = o;
}

// ---------------- V transpose: qkv[s][2560+kvh*64+d] -> vt[(b,kvh,d)][s] ----------------
__global__ void rope_v_kernel(const bf16* __restrict__ qkv, bf16* __restrict__ vt) {
    const int t = threadIdx.x;
    const int so = t & 63;
    const int dq = t >> 6;
    const int bk = blockIdx.y;
    const int s = blockIdx.x * 64 + so;
    const int b = bk >> 3;
    const bf16* src = qkv + ((size_t)b * SEQ + s) * QKVD + DIM + KVD + (bk & 7) * HD + dq * 16;
    short8 v0 = *(const short8*)src;
    short8 v1 = *(const short8*)(src + 8);
    short* dst = (short*)(vt + ((size_t)bk * HD + dq * 16) * SEQ + s);
#pragma unroll
    for (int j = 0; j < 8; j++) dst[(size_t)j * SEQ] = v0[j];
#pragma unroll
    for (int j = 0; j < 8; j++) dst[(size_t)(8 + j) * SEQ] = v1[j];
}

// ---------------- Flash attention (frozen: 93 us verified, counters stable) ----------------
__global__ __launch_bounds__(256, 4) void attn_kernel(const bf16* __restrict__ qr,
                                                      const bf16* __restrict__ kr,
                                                      const bf16* __restrict__ vt,
                                                      bf16* __restrict__ out) {
    __shared__ bf16 Ks[8192];
    __shared__ bf16 Vs[8192];
    const int t = threadIdx.x;
    const int lane = t & 63;
    const int wv = t >> 6;
    const int quad = lane >> 4;
    const int r16 = lane & 15;

    const int wg = blockIdx.x;
    const int xcd = wg & 7;
    const int kk = wg >> 3;
    const int bk = xcd * 2 + (kk & 1);
    const int qt = 127 - (kk >> 1);
    const int b = bk >> 3;
    const int kvh = bk & 7;
    const int h = kvh * 4 + wv;
    const int q0 = qt * 16;
    const int nkb = (qt >> 2) + 1;

    const bf16* Kg = kr + ((size_t)b * SEQ + lane) * KVD + kvh * HD + wv * 8;
    const bf16* Vg = vt + ((size_t)(b * NKV + kvh) * HD + lane) * SEQ + wv * 8;

    const char* kl = (const char*)Ks + quad * 1024 + r16 * 16;
    const char* vl = (const char*)Vs + (quad >> 1) * 1024 + r16 * 16 + (quad & 1) * 8;

    union PB { short4v s; unsigned u[2]; };

    const short one_bf16 = (short)0x3F80;
    const short4v ones = {one_bf16, one_bf16, one_bf16, one_bf16};

    const bf16* Qp = qr + ((size_t)b * SEQ + q0 + r16) * DIM + h * HD + quad * 8;
    short8 qa0 = *(const short8*)(Qp);
    short8 qa1 = *(const short8*)(Qp + 32);

    f32x4 o[4] = {};
    f32x4 o_l = {};

    {
        bf16* Ksd = Ks + t * 8;
        bf16* Vsd = Vs + t * 8;
        gld_lds16(Kg, Ksd);      gld_lds16(Kg + 32, Ksd + 2048);
        gld_lds16(Vg, Vsd);      gld_lds16(Vg + 32, Vsd + 2048);
    }

    for (int kb = 0; kb < nkb; kb++) {
        __syncthreads();
        const int buf = kb & 1;
        if (kb + 1 < nkb) {
            const bf16* Kgn = Kg + (size_t)(kb + 1) * 64 * KVD;
            const bf16* Vgn = Vg + (kb + 1) * 64;
            bf16* Ksd = Ks + (buf ^ 1) * 4096 + t * 8;
            bf16* Vsd = Vs + (buf ^ 1) * 4096 + t * 8;
            gld_lds16(Kgn, Ksd);      gld_lds16(Kgn + 32, Ksd + 2048);
            gld_lds16(Vgn, Vsd);      gld_lds16(Vgn + 32, Vsd + 2048);
        }
        const char* klb = kl + buf * 8192;
        const char* vlb = vl + buf * 8192;

        const f32x4 z = {0.f, 0.f, 0.f, 0.f};
        f32x4 st[4];
        __builtin_amdgcn_s_setprio(1);
#pragma unroll
        for (int n = 0; n < 4; n++) {
            short8 kf0 = *(const short8*)(klb + n * 256);
            short8 kf1 = *(const short8*)(klb + 4096 + n * 256);
            st[n] = __builtin_amdgcn_mfma_f32_16x16x32_bf16(kf0, qa0, z, 0, 0, 0);
            st[n] = __builtin_amdgcn_mfma_f32_16x16x32_bf16(kf1, qa1, st[n], 0, 0, 0);
        }
        __builtin_amdgcn_s_setprio(0);

        short4v vf[4][4];
#pragma unroll
        for (int dt = 0; dt < 4; dt++)
#pragma unroll
            for (int n = 0; n < 4; n++)
                vf[dt][n] = *(const short4v*)(vlb + n * 2048 + dt * 256);
        __builtin_amdgcn_sched_barrier(0);

        if (kb == nkb - 1) {
            const int kbase = kb * 64;
#pragma unroll
            for (int n = 0; n < 4; n++)
#pragma unroll
                for (int r = 0; r < 4; r++) {
                    int key = kbase + n * 16 + quad * 4 + r;
                    if (key > q0 + r16) st[n][r] = -__builtin_inff();
                }
        }

        PB pbs[4];
#pragma unroll
        for (int n = 0; n < 4; n++) {
            float p0 = exp2f(st[n][0]);
            float p1 = exp2f(st[n][1]);
            float p2 = exp2f(st[n][2]);
            float p3 = exp2f(st[n][3]);
            pbs[n].u[0] = pkbf16(p0, p1);
            pbs[n].u[1] = pkbf16(p2, p3);
        }

        __builtin_amdgcn_s_setprio(1);
#pragma unroll
        for (int dt = 0; dt < 4; dt++)
#pragma unroll
            for (int n = 0; n < 4; n++)
                o[dt] = __builtin_amdgcn_mfma_f32_16x16x16bf16_1k(vf[dt][n], pbs[n].s, o[dt], 0, 0, 0);
#pragma unroll
        for (int n = 0; n < 4; n++)
            o_l = __builtin_amdgcn_mfma_f32_16x16x16bf16_1k(ones, pbs[n].s, o_l, 0, 0, 0);
        __builtin_amdgcn_s_setprio(0);
    }

    float inv_l = 1.f / o_l[0];
    bf16* Op = out + ((size_t)b * SEQ + q0 + r16) * DIM + h * HD + quad * 4;
#pragma unroll
    for (int dt = 0; dt < 4; dt++) {
        PB pk;
        pk.u[0] = pkbf16(o[dt][0] * inv_l, o[dt][1] * inv_l);
        pk.u[1] = pkbf16(o[dt][2] * inv_l, o[dt][3] * inv_l);
        *(short4v*)(Op + dt * 16) = pk.s;
    }
}

extern "C" void kernel_launch(void* const* d_in, const int* in_sizes, int n_in,
                              void* d_out, int out_size, void* d_ws, size_t ws_size,
                              hipStream_t stream) {
    (void)in_sizes; (void)n_in; (void)out_size; (void)ws_size;
    const float* x    = (const float*)d_in[0];
    const float* fc   = (const float*)d_in[1];
    const float* wqkv = (const float*)d_in[3];
    const float* wo   = (const float*)d_in[4];
    float* out = (float*)d_out;

    char* w = (char*)d_ws;
    bf16* xb    = (bf16*)(w);
    bf16* wqkvb = (bf16*)(w + 16777216);
    bf16* wob   = (bf16*)(w + 29360128);
    bf16* qkvb  = (bf16*)(w + 37748736);
    bf16* kr    = (bf16*)(w + 62914560);
    bf16* vt    = (bf16*)(w + 67108864);
    bf16* qr = xb;
    bf16* attnb = qkvb;

    cvt3_kernel<<<18432, 256, 0, stream>>>(x, wqkv, wo, xb);
    gemm8p<bf16><<<dim3(12, 16), 512, 0, stream>>>(xb, wqkvb, qkvb, QKVD, DIM);   // A-arm: 8-phase qkv
    rope_qk_kernel<<<dim3(5, 4096), 64, 0, stream>>>(qkvb, fc, qr, kr);
    rope_v_kernel<<<dim3(32, 16), 256, 0, stream>>>(qkvb, vt);
    attn_kernel<<<dim3(2048), 256, 0, stream>>>(qr, kr, vt, attnb);
    gemm_nt<float><<<dim3(16, 32), 256, 0, stream>>>(attnb, wob, out, 4096, DIM, DIM);  // B-arm: m97 wo (100% fill)
}